// Round 7
// baseline (34.132 us; speedup 1.0000x reference)
//
#include <hip/hip_runtime.h>
#include <math.h>

// ---------------------------------------------------------------------------
// YOLO loss, forward only — 2 dispatches, 0 memsets, 0 inter-block protocols.
//   main (384 blocks):
//     1. issue this thread's dense-obj float4 loads (latency hidden by 2.)
//     2. EVERY block redundantly builds the full target-assignment hash
//        table in its own LDS (512 targets; CAS claim + atomicMax scan-order
//        + atomicOr target-mask). Contents are order-independent.
//     3. positives partitioned deterministically by cell % 384 == blockIdx:
//        no global list/count/flag/done — each block serves its ~4 owned
//        cells with its 4 waves (class loss spread over 80 lanes, box
//        GIoU+L1 + obj t=0->1 correction on lane 0).
//     4. block reduces {obj, cls, box, npos} -> dpart[bid] (disjoint).
//   finalize (1 block): deterministic reduction of 384x4 partials -> loss.
// Round-5/6 lesson: flag-spin cost ~20us, done-counter+list round-trip ~5us;
// kernel boundaries ~1us/node. Redundant compute beats synchronization here.
// ---------------------------------------------------------------------------

#define IMGF 640.0f
#define NCLS 80
#define NAK 3
#define NB 16
#define NT 32
#define H0 80
#define H1 40
#define H2 20
#define NCELL0 (NB * NAK * H0 * H0) /* 307200 */
#define NCELL1 (NB * NAK * H1 * H1) /*  76800 */
#define NCELL2 (NB * NAK * H2 * H2) /*  19200 */
#define NCELL_TOTAL (NCELL0 + NCELL1 + NCELL2) /* 403200 */
#define MAXPOS 1536 /* <=3 unique cells per target x 512 targets */
#define NDENSE (NCELL_TOTAL / 4) /* 100800 float4 groups */
#define NBLKF 384
#define HSIZE 2048 /* >= MAXPOS/0.75; 11-bit hash */

__device__ __constant__ float c_anchors[9][2] = {
    {0.0156f, 0.0203f}, {0.025f, 0.0469f}, {0.0516f, 0.0359f},
    {0.0469f, 0.0953f}, {0.0969f, 0.0703f}, {0.0922f, 0.1859f},
    {0.1813f, 0.1406f}, {0.2438f, 0.3094f}, {0.5828f, 0.5094f}};

__device__ inline float sgm(float x) { return 1.f / (1.f + expf(-x)); }
__device__ inline float bcef(float x, float t) {
    return fmaxf(x, 0.f) - x * t + log1pf(expf(-fabsf(x)));
}
__device__ inline float focal_bce(float x, float t) {
    float p = sgm(x);
    float pt = p * t + (1.f - p) * (1.f - t);
    float at = 0.25f * t + 0.75f * (1.f - t);
    float omp = 1.f - pt;
    return at * omp * omp * bcef(x, t);
}

// address of the float4 obj-group for dense index i4 (=cell/4), plus 1/NCELLs
__device__ inline const float* objaddr(const float* __restrict__ p0,
                                       const float* __restrict__ p1,
                                       const float* __restrict__ p2, int c4,
                                       float& inv) {
    if (c4 < NCELL0) {
        inv = 1.f / (float)NCELL0;
        int q = c4 / (H0 * H0);
        return p0 + ((size_t)q * 85 + 4) * (H0 * H0) + (c4 - q * (H0 * H0));
    } else if (c4 < NCELL0 + NCELL1) {
        inv = 1.f / (float)NCELL1;
        c4 -= NCELL0;
        int q = c4 / (H1 * H1);
        return p1 + ((size_t)q * 85 + 4) * (H1 * H1) + (c4 - q * (H1 * H1));
    } else {
        inv = 1.f / (float)NCELL2;
        c4 -= NCELL0 + NCELL1;
        int q = c4 / (H2 * H2);
        return p2 + ((size_t)q * 85 + 4) * (H2 * H2) + (c4 - q * (H2 * H2));
    }
}

__device__ inline float fb4_zero(float4 v) {
    return focal_bce(v.x, 0.f) + focal_bce(v.y, 0.f) + focal_bce(v.z, 0.f) +
           focal_bce(v.w, 0.f);
}

__global__ __launch_bounds__(256) void yolo_main(
    const float* __restrict__ p0, const float* __restrict__ p1,
    const float* __restrict__ p2, const float* __restrict__ boxes,
    const int* __restrict__ labels, float* __restrict__ dpart) {
    __shared__ int hkey[HSIZE];
    __shared__ int hord[HSIZE];
    __shared__ unsigned htm[HSIZE];
    __shared__ int qslots[MAXPOS];
    __shared__ int qn;
    __shared__ float redf[4][4];

    const int tid = threadIdx.x;
    const int bid = blockIdx.x;

    // ---- 1. issue dense obj loads now; consumed after assign ----
    int i0 = bid * 256 + tid;           // always < NDENSE (98304 < 100800)
    int i1 = i0 + NBLKF * 256;          // tail: only i0 < 2496 have i1 valid
    float inv0, inv1 = 0.f;
    const float4 v0 =
        *reinterpret_cast<const float4*>(objaddr(p0, p1, p2, i0 * 4, inv0));
    float4 v1 = make_float4(0.f, 0.f, 0.f, 0.f);
    const bool has1 = (i1 < NDENSE);
    if (has1)
        v1 = *reinterpret_cast<const float4*>(
            objaddr(p0, p1, p2, i1 * 4, inv1));

    // ---- 2. redundant assignment: full hash table per block ----
    for (int i = tid; i < HSIZE; i += 256) {
        hkey[i] = -1;
        hord[i] = -1;
        htm[i] = 0u;
    }
    if (tid == 0) qn = 0;
    __syncthreads();
    for (int half = 0; half < 2; half++) {
        int t = tid + (half << 8);
        int b = t >> 5;
        int n = t & 31;
        int lab = labels[t];
        if (lab >= 0 && lab < NCLS) {
            float x1 = boxes[4 * t + 0], y1 = boxes[4 * t + 1];
            float x2 = boxes[4 * t + 2], y2 = boxes[4 * t + 3];
            float bw = fminf(fmaxf((x2 - x1) / IMGF, 1e-6f), 1.0f);
            float bh = fminf(fmaxf((y2 - y1) / IMGF, 1e-6f), 1.0f);
            float area = bw * bh;
            float best = -1.0f;
            int bestk = 0;
#pragma unroll
            for (int k = 0; k < 9; k++) { // strict > == jnp.argmax first-max
                float aw = c_anchors[k][0], ah = c_anchors[k][1];
                float inter = fminf(bw, aw) * fminf(bh, ah);
                float iou = inter / (area + aw * ah - inter + 1e-9f);
                if (iou > best) { best = iou; bestk = k; }
            }
            int s = bestk / 3, a = bestk - 3 * s;
            float cx = fminf(fmaxf((x1 + x2) * 0.5f / IMGF, 0.f), 1.f - 1e-6f);
            float cy = fminf(fmaxf((y1 + y2) * 0.5f / IMGF, 0.f), 1.f - 1e-6f);
            int hw = (s == 0) ? H0 : ((s == 1) ? H1 : H2);
            int basecell =
                (s == 0) ? 0 : ((s == 1) ? NCELL0 : (NCELL0 + NCELL1));
            float gx = cx * (float)hw, gy = cy * (float)hw;
            int gi = min(max((int)floorf(gx), 0), hw - 1);
            int gj = min(max((int)floorf(gy), 0), hw - 1);
            float fx = gx - (float)gi, fy = gy - (float)gj;
            const int dis[5] = {0, -1, 1, 0, 0};
            const int djs[5] = {0, 0, 0, -1, 1};
            bool keep[5];
            keep[0] = true;
            keep[1] = (fx < 0.5f);
            keep[2] = (fx >= 0.5f);
            keep[3] = (fy < 0.5f);
            keep[4] = (fy >= 0.5f);
#pragma unroll
            for (int c = 0; c < 5; c++) {
                if (!keep[c]) continue;
                int ngi = gi + dis[c], ngj = gj + djs[c];
                if (ngi < 0 || ngi >= hw || ngj < 0 || ngj >= hw) continue;
                int cell = basecell + ((b * NAK + a) * hw + ngj) * hw + ngi;
                unsigned h = ((unsigned)cell * 2654435761u) >> 21; // 11 bits
                while (true) {
                    int old = atomicCAS(&hkey[h], -1, cell);
                    if (old == -1 || old == cell) break;
                    h = (h + 1) & (HSIZE - 1);
                }
                // scan-order key: last-writer-wins (XLA scatter-set); the
                // table CONTENTS are race-order-independent (max/or).
                atomicMax(&hord[h], c * (NB * NT) + t);
                atomicOr(&htm[h], 1u << n);
            }
        }
    }
    __syncthreads();

    // ---- 3a. collect owned positives: cell % NBLKF == bid ----
    for (int i = tid; i < HSIZE; i += 256) {
        int k = hkey[i];
        if (k >= 0 && (k % NBLKF) == bid) {
            int p = atomicAdd(&qn, 1);
            qslots[p] = i;
        }
    }

    // ---- dense obj from the preloaded values (t = 0 baseline) ----
    float obj_c = fb4_zero(v0) * inv0;
    if (has1) obj_c += fb4_zero(v1) * inv1;

    __syncthreads(); // qn/qslots ready
    const int nq = qn;

    // ---- 3b. owned positives: one wave per cell ----
    const int wv = tid >> 6;
    const int lane = tid & 63;
    float cls_a = 0.f, box_a = 0.f, objc_a = 0.f;
    for (int qi = wv; qi < nq; qi += 4) {
        int slot = qslots[qi];
        int idx = hkey[slot];
        unsigned tm = htm[slot];
        int ord = hord[slot];
        const float* p;
        int hw, s, base;
        float inv;
        if (idx < NCELL0) {
            p = p0; hw = H0; s = 0; base = 0; inv = 1.f / (float)NCELL0;
        } else if (idx < NCELL0 + NCELL1) {
            p = p1; hw = H1; s = 1; base = NCELL0; inv = 1.f / (float)NCELL1;
        } else {
            p = p2; hw = H2; s = 2; base = NCELL0 + NCELL1;
            inv = 1.f / (float)NCELL2;
        }
        int cell = idx - base;
        int x = cell % hw;
        int r = cell / hw;
        int y = r % hw;
        r /= hw;
        int a = r % NAK;
        int b = r / NAK;
        size_t HW = (size_t)hw * hw;
        const float* pc =
            p + (size_t)(b * 255 + a * 85) * HW + (size_t)y * hw + x;
        // class loss: 80 classes spread over lanes (2 parallel rounds)
        float cl = 0.f;
#pragma unroll
        for (int rep = 0; rep < 2; rep++) {
            int c = lane + 64 * rep;
            if (c < NCLS) {
                float tt = 0.f;
                unsigned tmp = tm;
                while (tmp) {
                    int n = __ffs(tmp) - 1;
                    tmp &= tmp - 1;
                    if (labels[(b << 5) + n] == c) tt = 1.f;
                }
                cl += bcef(pc[(size_t)(5 + c) * HW], tt);
            }
        }
#pragma unroll
        for (int off = 32; off > 0; off >>= 1) cl += __shfl_down(cl, off, 64);
        if (lane == 0) {
            cls_a += cl;
            // obj correction t=0 -> t=1 (dense pass assumed t=0)
            float pobj = pc[4 * HW];
            objc_a += (focal_bce(pobj, 1.f) - focal_bce(pobj, 0.f)) * inv;
            // box loss: decode last scatter writer
            int wn = ord & (NB * NT - 1); // order % 512
            float bx1 = boxes[4 * wn + 0], by1 = boxes[4 * wn + 1];
            float bx2 = boxes[4 * wn + 2], by2 = boxes[4 * wn + 3];
            float tw = fminf(fmaxf((bx2 - bx1) / IMGF, 1e-6f), 1.f);
            float th = fminf(fmaxf((by2 - by1) / IMGF, 1e-6f), 1.f);
            float tcx =
                fminf(fmaxf((bx1 + bx2) * 0.5f / IMGF, 0.f), 1.f - 1e-6f);
            float tcy =
                fminf(fmaxf((by1 + by2) * 0.5f / IMGF, 0.f), 1.f - 1e-6f);
            float l0 = pc[0], l1 = pc[HW], l2 = pc[2 * HW], l3 = pc[3 * HW];
            float pcx = ((float)x + 2.f * sgm(l0) - 0.5f) / (float)hw;
            float pcy = ((float)y + 2.f * sgm(l1) - 0.5f) / (float)hw;
            float sw = 2.f * sgm(l2), sh = 2.f * sgm(l3);
            float pw = sw * sw * c_anchors[s * 3 + a][0];
            float ph = sh * sh * c_anchors[s * 3 + a][1];
            float px1 = pcx - pw * 0.5f, px2 = pcx + pw * 0.5f;
            float py1 = pcy - ph * 0.5f, py2 = pcy + ph * 0.5f;
            float tx1 = tcx - tw * 0.5f, tx2 = tcx + tw * 0.5f;
            float ty1 = tcy - th * 0.5f, ty2 = tcy + th * 0.5f;
            float iw = fmaxf(fminf(px2, tx2) - fmaxf(px1, tx1), 0.f);
            float ih = fmaxf(fminf(py2, ty2) - fmaxf(py1, ty1), 0.f);
            float it = iw * ih;
            float un = pw * ph + tw * th - it + 1e-9f;
            float iou = it / un;
            float enc = (fmaxf(px2, tx2) - fminf(px1, tx1)) *
                            (fmaxf(py2, ty2) - fminf(py1, ty1)) +
                        1e-9f;
            float giou = iou - (enc - un) / enc;
            float l1l = fabsf(pcx - tcx) + fabsf(pcy - tcy) + fabsf(pw - tw) +
                        fabsf(ph - th);
            box_a += 1.f - giou + l1l;
        }
    }

    // ---- 4. block reduce {obj(dense+corr), cls, box} ----
    float s_obj = obj_c + objc_a; // objc_a nonzero only on lane 0
#pragma unroll
    for (int off = 32; off > 0; off >>= 1) {
        s_obj += __shfl_down(s_obj, off, 64);
        cls_a += __shfl_down(cls_a, off, 64);
        box_a += __shfl_down(box_a, off, 64);
    }
    if (lane == 0) {
        redf[wv][0] = s_obj;
        redf[wv][1] = cls_a;
        redf[wv][2] = box_a;
    }
    __syncthreads();
    if (tid == 0) {
        float* dst = dpart + (size_t)bid * 4;
        dst[0] = redf[0][0] + redf[1][0] + redf[2][0] + redf[3][0];
        dst[1] = redf[0][1] + redf[1][1] + redf[2][1] + redf[3][1];
        dst[2] = redf[0][2] + redf[1][2] + redf[2][2] + redf[3][2];
        dst[3] = (float)nq; // owned-positive count
    }
}

// 1 block: deterministic reduction of NBLKF x 4 partials -> scalar loss.
__global__ __launch_bounds__(256) void yolo_finalize(
    const float* __restrict__ dpart, float* __restrict__ out) {
    float o = 0.f, cls = 0.f, box = 0.f, np = 0.f;
    for (int i = threadIdx.x; i < NBLKF; i += 256) {
        const float* src = dpart + (size_t)i * 4;
        o += src[0];
        cls += src[1];
        box += src[2];
        np += src[3];
    }
#pragma unroll
    for (int off = 32; off > 0; off >>= 1) {
        o += __shfl_down(o, off, 64);
        cls += __shfl_down(cls, off, 64);
        box += __shfl_down(box, off, 64);
        np += __shfl_down(np, off, 64);
    }
    __shared__ float red[4][4];
    int wv = threadIdx.x >> 6;
    if ((threadIdx.x & 63) == 0) {
        red[wv][0] = o;
        red[wv][1] = cls;
        red[wv][2] = box;
        red[wv][3] = np;
    }
    __syncthreads();
    if (threadIdx.x == 0) {
        float oo = red[0][0] + red[1][0] + red[2][0] + red[3][0];
        float cc = red[0][1] + red[1][1] + red[2][1] + red[3][1];
        float bb = red[0][2] + red[1][2] + red[2][2] + red[3][2];
        float nn = red[0][3] + red[1][3] + red[2][3] + red[3][3];
        float d = fmaxf(nn, 1.f);
        out[0] = oo + (cc + 5.f * bb) / d;
    }
}

extern "C" void kernel_launch(void* const* d_in, const int* in_sizes, int n_in,
                              void* d_out, int out_size, void* d_ws,
                              size_t ws_size, hipStream_t stream) {
    const float* p0 = (const float*)d_in[0];
    const float* p1 = (const float*)d_in[1];
    const float* p2 = (const float*)d_in[2];
    const float* boxes = (const float*)d_in[3];
    const int* labels = (const int*)d_in[4];
    float* out = (float*)d_out;

    // ws: [dpart f32 x NBLKF*4] — fully written by yolo_main every call.
    float* dpart = (float*)d_ws;

    yolo_main<<<NBLKF, 256, 0, stream>>>(p0, p1, p2, boxes, labels, dpart);
    yolo_finalize<<<1, 256, 0, stream>>>(dpart, out);
}

// Round 8
// 29.892 us; speedup vs baseline: 1.1419x; 1.1419x over previous
//
#include <hip/hip_runtime.h>
#include <math.h>

// ---------------------------------------------------------------------------
// YOLO loss, forward only — 2 dispatches, 0 memsets, 0 spin protocols.
//   k1 : block 0 runs the target assignment (LDS hash dedup: CAS claim +
//        atomicMax scan-order + atomicOr target-mask) -> list+count, resets
//        done. Block 0 is dispatched FIRST so the assign work is hidden
//        under blocks 1..384 streaming the obj channel (focal-BCE t=0
//        baseline, coalesced float4) -> dpart[bid-1].
//        Kernel boundary = synchronization (round-5 lesson: intra-kernel
//        flag/arrive protocols cost ~20us; boundaries cost ~1us/node).
//   k2 : one wave per positive cell — obj correction (t=0 -> t=1), class
//        loss spread over 80 lanes, box GIoU+L1 on lane 0; last-done block
//        (done-counter protocol) reduces dpart+ppart, writes scalar loss.
// Round-7 lesson: redundant per-block assignment (no sync at all) costs more
// than the sync it removes — revert to the proven round-6 structure.
// ---------------------------------------------------------------------------

#define IMGF 640.0f
#define NCLS 80
#define NAK 3
#define NB 16
#define NT 32
#define H0 80
#define H1 40
#define H2 20
#define NCELL0 (NB * NAK * H0 * H0) /* 307200 */
#define NCELL1 (NB * NAK * H1 * H1) /*  76800 */
#define NCELL2 (NB * NAK * H2 * H2) /*  19200 */
#define NCELL_TOTAL (NCELL0 + NCELL1 + NCELL2) /* 403200 */
#define MAXPOS 1536 /* <=3 unique cells per target x 512 targets */
#define NDENSE (NCELL_TOTAL / 4) /* 100800 float4 groups */
#define NBLK_D 384               /* dense blocks in k1 (blocks 1..384) */
#define POS_BLOCKS 384           /* k2 blocks: 4 waves each = 1536 waves */
#define HSIZE 4096

__device__ __constant__ float c_anchors[9][2] = {
    {0.0156f, 0.0203f}, {0.025f, 0.0469f}, {0.0516f, 0.0359f},
    {0.0469f, 0.0953f}, {0.0969f, 0.0703f}, {0.0922f, 0.1859f},
    {0.1813f, 0.1406f}, {0.2438f, 0.3094f}, {0.5828f, 0.5094f}};

__device__ inline float sgm(float x) { return 1.f / (1.f + expf(-x)); }
__device__ inline float bcef(float x, float t) {
    return fmaxf(x, 0.f) - x * t + log1pf(expf(-fabsf(x)));
}
__device__ inline float focal_bce(float x, float t) {
    float p = sgm(x);
    float pt = p * t + (1.f - p) * (1.f - t);
    float at = 0.25f * t + 0.75f * (1.f - t);
    float omp = 1.f - pt;
    return at * omp * omp * bcef(x, t);
}

template <int HWC>
__device__ inline float obj4(const float* __restrict__ p, int cis, float inv) {
    int q = cis / HWC; // (b*3+a); compile-time divisor -> magic mul
    int off = cis - q * HWC;
    const float4 v =
        *reinterpret_cast<const float4*>(p + ((size_t)q * 85 + 4) * HWC + off);
    return (focal_bce(v.x, 0.f) + focal_bce(v.y, 0.f) + focal_bce(v.z, 0.f) +
            focal_bce(v.w, 0.f)) *
           inv;
}

// ---------------- k1: assign (block 0, first) + dense obj stream ----------------
__global__ __launch_bounds__(256) void k1_dense_assign(
    const float* __restrict__ p0, const float* __restrict__ p1,
    const float* __restrict__ p2, const float* __restrict__ boxes,
    const int* __restrict__ labels, int4* __restrict__ list,
    int* __restrict__ countg, int* __restrict__ done,
    float* __restrict__ dpart) {
    if (blockIdx.x == 0) {
        // ---- assign: LDS hash dedup over 512 targets (hidden under dense) ----
        __shared__ int hkey[HSIZE];
        __shared__ int hord[HSIZE];
        __shared__ unsigned htm[HSIZE];
        __shared__ int lcount;
        for (int i = threadIdx.x; i < HSIZE; i += 256) {
            hkey[i] = -1;
            hord[i] = -1;
            htm[i] = 0u;
        }
        if (threadIdx.x == 0) lcount = 0;
        __syncthreads();
        for (int half = 0; half < 2; half++) {
            int t = threadIdx.x + (half << 8);
            int b = t >> 5;
            int n = t & 31;
            int lab = labels[t];
            if (lab >= 0 && lab < NCLS) {
                float x1 = boxes[4 * t + 0], y1 = boxes[4 * t + 1];
                float x2 = boxes[4 * t + 2], y2 = boxes[4 * t + 3];
                float bw = fminf(fmaxf((x2 - x1) / IMGF, 1e-6f), 1.0f);
                float bh = fminf(fmaxf((y2 - y1) / IMGF, 1e-6f), 1.0f);
                float area = bw * bh;
                float best = -1.0f;
                int bestk = 0;
#pragma unroll
                for (int k = 0; k < 9; k++) { // strict > == argmax first-max
                    float aw = c_anchors[k][0], ah = c_anchors[k][1];
                    float inter = fminf(bw, aw) * fminf(bh, ah);
                    float iou = inter / (area + aw * ah - inter + 1e-9f);
                    if (iou > best) { best = iou; bestk = k; }
                }
                int s = bestk / 3, a = bestk - 3 * s;
                float cx =
                    fminf(fmaxf((x1 + x2) * 0.5f / IMGF, 0.f), 1.f - 1e-6f);
                float cy =
                    fminf(fmaxf((y1 + y2) * 0.5f / IMGF, 0.f), 1.f - 1e-6f);
                int hw = (s == 0) ? H0 : ((s == 1) ? H1 : H2);
                int basecell =
                    (s == 0) ? 0 : ((s == 1) ? NCELL0 : (NCELL0 + NCELL1));
                float gx = cx * (float)hw, gy = cy * (float)hw;
                int gi = min(max((int)floorf(gx), 0), hw - 1);
                int gj = min(max((int)floorf(gy), 0), hw - 1);
                float fx = gx - (float)gi, fy = gy - (float)gj;
                const int dis[5] = {0, -1, 1, 0, 0};
                const int djs[5] = {0, 0, 0, -1, 1};
                bool keep[5];
                keep[0] = true;
                keep[1] = (fx < 0.5f);
                keep[2] = (fx >= 0.5f);
                keep[3] = (fy < 0.5f);
                keep[4] = (fy >= 0.5f);
#pragma unroll
                for (int c = 0; c < 5; c++) {
                    if (!keep[c]) continue;
                    int ngi = gi + dis[c], ngj = gj + djs[c];
                    if (ngi < 0 || ngi >= hw || ngj < 0 || ngj >= hw) continue;
                    int cell = basecell + ((b * NAK + a) * hw + ngj) * hw + ngi;
                    unsigned h = ((unsigned)cell * 2654435761u) >> 20;
                    while (true) {
                        int old = atomicCAS(&hkey[h], -1, cell);
                        if (old == -1 || old == cell) break;
                        h = (h + 1) & (HSIZE - 1);
                    }
                    // scan-order key: last-writer-wins (XLA scatter-set)
                    atomicMax(&hord[h], c * (NB * NT) + t);
                    atomicOr(&htm[h], 1u << n);
                }
            }
        }
        __syncthreads();
        for (int i = threadIdx.x; i < HSIZE; i += 256) {
            if (hkey[i] >= 0) {
                int p = atomicAdd(&lcount, 1);
                list[p] = make_int4(hkey[i], hord[i], (int)htm[i], 0);
            }
        }
        __syncthreads();
        if (threadIdx.x == 0) {
            *countg = lcount;
            *done = 0; // reset k2's finalize protocol
        }
        return;
    }
    // ---- dense obj: t = 0 baseline, pure coalesced stream ----
    float obj = 0.f;
    for (int i = (blockIdx.x - 1) * 256 + threadIdx.x; i < NDENSE;
         i += NBLK_D * 256) {
        int c4 = i * 4;
        if (c4 < NCELL0)
            obj += obj4<H0 * H0>(p0, c4, 1.f / (float)NCELL0);
        else if (c4 < NCELL0 + NCELL1)
            obj += obj4<H1 * H1>(p1, c4 - NCELL0, 1.f / (float)NCELL1);
        else
            obj += obj4<H2 * H2>(p2, c4 - NCELL0 - NCELL1, 1.f / (float)NCELL2);
    }
#pragma unroll
    for (int off = 32; off > 0; off >>= 1) obj += __shfl_down(obj, off, 64);
    __shared__ float redd[4];
    if ((threadIdx.x & 63) == 0) redd[threadIdx.x >> 6] = obj;
    __syncthreads();
    if (threadIdx.x == 0)
        dpart[blockIdx.x - 1] = redd[0] + redd[1] + redd[2] + redd[3];
}

// ---------------- k2: positives (one wave/cell) + fused finalize ----------------
__global__ __launch_bounds__(256) void k2_pos_finalize(
    const float* __restrict__ p0, const float* __restrict__ p1,
    const float* __restrict__ p2, const float* __restrict__ boxes,
    const int* __restrict__ labels, const int4* __restrict__ list,
    const int* __restrict__ countg, int* __restrict__ done,
    const float* __restrict__ dpart, float* __restrict__ ppart,
    float* __restrict__ out) {
    int cnt = *countg;
    int w = blockIdx.x * 4 + (threadIdx.x >> 6);
    int lane = threadIdx.x & 63;
    if (w < cnt) {
        int4 rec = list[w];
        int idx = rec.x;
        unsigned tm = (unsigned)rec.z;
        const float* p;
        int hw, s, base;
        float inv;
        if (idx < NCELL0) {
            p = p0; hw = H0; s = 0; base = 0; inv = 1.f / (float)NCELL0;
        } else if (idx < NCELL0 + NCELL1) {
            p = p1; hw = H1; s = 1; base = NCELL0; inv = 1.f / (float)NCELL1;
        } else {
            p = p2; hw = H2; s = 2; base = NCELL0 + NCELL1;
            inv = 1.f / (float)NCELL2;
        }
        int cell = idx - base;
        int x = cell % hw;
        int r = cell / hw;
        int y = r % hw;
        r /= hw;
        int a = r % NAK;
        int b = r / NAK;
        size_t HW = (size_t)hw * hw;
        const float* pc =
            p + (size_t)(b * 255 + a * 85) * HW + (size_t)y * hw + x;
        // class loss: 80 classes spread over lanes (2 parallel rounds)
        float cl = 0.f;
#pragma unroll
        for (int rep = 0; rep < 2; rep++) {
            int c = lane + 64 * rep;
            if (c < NCLS) {
                float tt = 0.f;
                unsigned tmp = tm;
                while (tmp) {
                    int n = __ffs(tmp) - 1;
                    tmp &= tmp - 1;
                    if (labels[(b << 5) + n] == c) tt = 1.f;
                }
                cl += bcef(pc[(size_t)(5 + c) * HW], tt);
            }
        }
#pragma unroll
        for (int off = 32; off > 0; off >>= 1) cl += __shfl_down(cl, off, 64);
        if (lane == 0) {
            // obj correction t=0 -> t=1 (k1 assumed t=0 everywhere)
            float pobj = pc[4 * HW];
            float objc = (focal_bce(pobj, 1.f) - focal_bce(pobj, 0.f)) * inv;
            // box loss: decode last scatter writer
            int wn = rec.y & (NB * NT - 1); // order % 512
            float bx1 = boxes[4 * wn + 0], by1 = boxes[4 * wn + 1];
            float bx2 = boxes[4 * wn + 2], by2 = boxes[4 * wn + 3];
            float tw = fminf(fmaxf((bx2 - bx1) / IMGF, 1e-6f), 1.f);
            float th = fminf(fmaxf((by2 - by1) / IMGF, 1e-6f), 1.f);
            float tcx =
                fminf(fmaxf((bx1 + bx2) * 0.5f / IMGF, 0.f), 1.f - 1e-6f);
            float tcy =
                fminf(fmaxf((by1 + by2) * 0.5f / IMGF, 0.f), 1.f - 1e-6f);
            float l0 = pc[0], l1 = pc[HW], l2 = pc[2 * HW], l3 = pc[3 * HW];
            float pcx = ((float)x + 2.f * sgm(l0) - 0.5f) / (float)hw;
            float pcy = ((float)y + 2.f * sgm(l1) - 0.5f) / (float)hw;
            float sw = 2.f * sgm(l2), sh = 2.f * sgm(l3);
            float pw = sw * sw * c_anchors[s * 3 + a][0];
            float ph = sh * sh * c_anchors[s * 3 + a][1];
            float px1 = pcx - pw * 0.5f, px2 = pcx + pw * 0.5f;
            float py1 = pcy - ph * 0.5f, py2 = pcy + ph * 0.5f;
            float tx1 = tcx - tw * 0.5f, tx2 = tcx + tw * 0.5f;
            float ty1 = tcy - th * 0.5f, ty2 = tcy + th * 0.5f;
            float iw = fmaxf(fminf(px2, tx2) - fmaxf(px1, tx1), 0.f);
            float ih = fmaxf(fminf(py2, ty2) - fmaxf(py1, ty1), 0.f);
            float it = iw * ih;
            float un = pw * ph + tw * th - it + 1e-9f;
            float iou = it / un;
            float enc = (fmaxf(px2, tx2) - fminf(px1, tx1)) *
                            (fmaxf(py2, ty2) - fminf(py1, ty1)) +
                        1e-9f;
            float giou = iou - (enc - un) / enc;
            float l1l = fabsf(pcx - tcx) + fabsf(pcy - tcy) + fabsf(pw - tw) +
                        fabsf(ph - th);
            ppart[3 * w] = cl;
            ppart[3 * w + 1] = 1.f - giou + l1l;
            ppart[3 * w + 2] = objc;
        }
    }
    // ---- fused finalize: last block to finish reduces everything ----
    __shared__ int amLast;
    __syncthreads();
    if (threadIdx.x == 0) {
        __threadfence(); // release our partial writes
        amLast = (atomicAdd(done, 1) == POS_BLOCKS - 1) ? 1 : 0;
    }
    __syncthreads();
    if (amLast) {
        __threadfence(); // acquire other blocks' writes
        float o = 0.f, cls = 0.f, box = 0.f;
        for (int i = threadIdx.x; i < NBLK_D; i += 256) o += dpart[i];
        for (int i = threadIdx.x; i < cnt; i += 256) {
            cls += ppart[3 * i];
            box += ppart[3 * i + 1];
            o += ppart[3 * i + 2];
        }
#pragma unroll
        for (int off = 32; off > 0; off >>= 1) {
            o += __shfl_down(o, off, 64);
            cls += __shfl_down(cls, off, 64);
            box += __shfl_down(box, off, 64);
        }
        __shared__ float redf[4][3];
        int wv = threadIdx.x >> 6;
        if ((threadIdx.x & 63) == 0) {
            redf[wv][0] = o;
            redf[wv][1] = cls;
            redf[wv][2] = box;
        }
        __syncthreads();
        if (threadIdx.x == 0) {
            float oo = redf[0][0] + redf[1][0] + redf[2][0] + redf[3][0];
            float cc = redf[0][1] + redf[1][1] + redf[2][1] + redf[3][1];
            float bb = redf[0][2] + redf[1][2] + redf[2][2] + redf[3][2];
            float d = fmaxf((float)cnt, 1.f);
            out[0] = oo + (cc + 5.f * bb) / d;
        }
    }
}

extern "C" void kernel_launch(void* const* d_in, const int* in_sizes, int n_in,
                              void* d_out, int out_size, void* d_ws,
                              size_t ws_size, hipStream_t stream) {
    const float* p0 = (const float*)d_in[0];
    const float* p1 = (const float*)d_in[1];
    const float* p2 = (const float*)d_in[2];
    const float* boxes = (const float*)d_in[3];
    const int* labels = (const int*)d_in[4];
    float* out = (float*)d_out;

    // ws layout (every region read is written earlier in the same call):
    // [list int4 x MAXPOS][countg][done][pad][dpart f32 x NBLK_D]
    // [ppart f32 x MAXPOS*3]
    char* ws = (char*)d_ws;
    int4* list = (int4*)ws;
    size_t off = (size_t)MAXPOS * 16; // 24576
    int* countg = (int*)(ws + off);
    int* done = (int*)(ws + off + 4);
    off += 16;
    float* dpart = (float*)(ws + off);
    off += (size_t)NBLK_D * 4;
    float* ppart = (float*)(ws + off);

    k1_dense_assign<<<NBLK_D + 1, 256, 0, stream>>>(p0, p1, p2, boxes, labels,
                                                    list, countg, done, dpart);
    k2_pos_finalize<<<POS_BLOCKS, 256, 0, stream>>>(p0, p1, p2, boxes, labels,
                                                    list, countg, done, dpart,
                                                    ppart, out);
}